// Round 10
// baseline (195.052 us; speedup 1.0000x reference)
//
#include <hip/hip_runtime.h>
#include <hip/hip_fp16.h>
#include <cstdint>
#include <cmath>

#define B_ 128
#define P_ 8732
#define QU_ 2183        // P_ / 4 exactly
#define M_ 16
#define NT 1024
#define NW 16           // waves per block == M_
#define NP9 9           // ceil(P_/NT)

__device__ __forceinline__ float softplusf(float x) {
    return fmaxf(x, 0.0f) + log1pf(expf(-fabsf(x)));
}

__device__ __forceinline__ float wred_sum_f(float v) {
#pragma unroll
    for (int o = 32; o > 0; o >>= 1) v += __shfl_down(v, o, 64);
    return v;
}
__device__ __forceinline__ int wred_sum_i(int v) {
#pragma unroll
    for (int o = 32; o > 0; o >>= 1) v += __shfl_down(v, o, 64);
    return v;
}

__device__ __forceinline__ float bce3(const float* sc, int lab) {
    float x0 = sc[0], x1 = sc[1], x2 = sc[2];
    float t0 = (lab == 0) ? 1.0f : 0.0f;
    float t1 = (lab == 1 || lab == 3) ? 1.0f : 0.0f;
    float t2 = (lab == 2 || lab == 3) ? 1.0f : 0.0f;
    return (softplusf(x0) - x0*t0) + (softplusf(x1) - x1*t1) + (softplusf(x2) - x2*t2);
}

// ============ K1: match + BCE/L1 (no-fixup assumption). grid = 512. ==========
// block bk: row r = bk>>2, quarter q = bk&3.
//  - objov[r][p]  = obj(4b) | pos(bit7)
//  - bcew[r][p]   = fp16 bce for negatives, 0 for positives
//  - pcf/plc/pnp[bk] = quarter partial conf_pos / loc_sum / n_pos
//  - cand[bk][m]  = per-object best-prior candidate in this quarter
__global__ __launch_bounds__(NT) void mbox_match_kernel(
    const float* __restrict__ plocs,   // (B,P,4)
    const float* __restrict__ pscores, // (B,P,3)
    const float* __restrict__ boxes,   // (B,M,4) xyxy
    const int*   __restrict__ labels,  // (B,M)
    const float* __restrict__ priors,  // (P,4) cxcy
    unsigned char* __restrict__ objov,
    unsigned short* __restrict__ bcew,
    int2* __restrict__ cand,
    float* __restrict__ pcf, float* __restrict__ plc, int* __restrict__ pnp,
    unsigned int* __restrict__ gz)     // 4 words to zero (g_cnt,g_conf,g_loc,g_np)
{
    __shared__ float s_boxes[M_ * 4];
    __shared__ float s_area[M_];
    __shared__ int   s_labels[M_];
    __shared__ float s_pf[2 * NW];
    __shared__ int   s_pi[NW];

    const int bk = blockIdx.x;
    const int r  = bk >> 2;
    const int q  = bk & 3;
    const int tid = threadIdx.x;
    const int lane = tid & 63;
    const int wid = tid >> 6;

    if (bk == 0 && tid < 4) gz[tid] = 0u;   // zero global accumulators for K2

    if (tid < M_ * 4) s_boxes[tid] = boxes[r * M_ * 4 + tid];
    if (tid >= 64 && tid < 64 + M_) s_labels[tid - 64] = labels[r * M_ + (tid - 64)];
    __syncthreads();
    if (tid < M_) {
        float x0 = s_boxes[tid*4+0], y0 = s_boxes[tid*4+1];
        float x1 = s_boxes[tid*4+2], y1 = s_boxes[tid*4+3];
        s_area[tid] = (x1 - x0) * (y1 - y0);
    }
    __syncthreads();

    const int p0 = q * QU_;

    // ---- Phase A+D fused: per-prior best object, then bce/l1 with that match
    int np = 0; float cp = 0.0f, ls = 0.0f;
    for (int p = p0 + tid; p < p0 + QU_; p += NT) {
        float4 pr = ((const float4*)priors)[p];
        float px0 = pr.x - pr.z * 0.5f;
        float py0 = pr.y - pr.w * 0.5f;
        float px1 = pr.x + pr.z * 0.5f;
        float py1 = pr.y + pr.w * 0.5f;
        float parea = pr.z * pr.w;
        float bestv = -1.0f; int besti = 0;
#pragma unroll
        for (int m = 0; m < M_; ++m) {
            float ltx = fmaxf(s_boxes[m*4+0], px0);
            float lty = fmaxf(s_boxes[m*4+1], py0);
            float rbx = fminf(s_boxes[m*4+2], px1);
            float rby = fminf(s_boxes[m*4+3], py1);
            float wx = fmaxf(rbx - ltx, 0.0f);
            float wy = fmaxf(rby - lty, 0.0f);
            float inter = wx * wy;
            float ov = inter * __builtin_amdgcn_rcpf(s_area[m] + parea - inter);
            if (ov > bestv) { bestv = ov; besti = m; }       // first-max over m
        }
        bool pos = bestv >= 0.5f;
        objov[(size_t)r * P_ + p] = (unsigned char)(besti | (pos ? 0x80 : 0));

        int lab = pos ? s_labels[besti] : 0;
        float bce = bce3(pscores + ((size_t)r * P_ + p) * 3, lab);
        float hb = 0.0f;
        if (pos) {
            np++; cp += bce;
            float bx0 = s_boxes[besti*4+0], by0 = s_boxes[besti*4+1];
            float bx1 = s_boxes[besti*4+2], by1 = s_boxes[besti*4+3];
            float cx = (bx0 + bx1) * 0.5f, cy = (by0 + by1) * 0.5f;
            float w = bx1 - bx0, hh = by1 - by0;
            float g0 = (cx - pr.x) / (pr.z * 0.1f);
            float g1 = (cy - pr.y) / (pr.w * 0.1f);
            float g2 = logf(w / pr.z) * 5.0f;
            float g3 = logf(hh / pr.w) * 5.0f;
            float4 pl = ((const float4*)plocs)[(size_t)r * P_ + p];
            ls += fabsf(pl.x - g0) + fabsf(pl.y - g1) + fabsf(pl.z - g2) + fabsf(pl.w - g3);
        } else {
            hb = bce;
        }
        __half h = __float2half(hb);
        bcew[(size_t)r * P_ + p] = __half_as_ushort(h);
    }

    // ---- reduce quarter partials
    {
        float cpr = wred_sum_f(cp);
        float lsr = wred_sum_f(ls);
        int   npr = wred_sum_i(np);
        if (lane == 0) { s_pf[wid] = cpr; s_pf[NW + wid] = lsr; s_pi[wid] = npr; }
    }
    __syncthreads();
    if (tid == 0) {
        float c2 = 0.0f, l2 = 0.0f; int n2 = 0;
#pragma unroll
        for (int w = 0; w < NW; ++w) { c2 += s_pf[w]; l2 += s_pf[NW + w]; n2 += s_pi[w]; }
        pcf[bk] = c2; plc[bk] = l2; pnp[bk] = n2;
    }

    // ---- Phase B: one WAVE per object, wave-argmax over the quarter
    {
        const int m = wid;
        float bx0 = s_boxes[m*4+0], by0 = s_boxes[m*4+1];
        float bx1 = s_boxes[m*4+2], by1 = s_boxes[m*4+3];
        float marea = s_area[m];
        float bv = -1.0f; int bi = 0x7FFFFFFF;
        for (int p = p0 + lane; p < p0 + QU_; p += 64) {
            float4 pr = ((const float4*)priors)[p];
            float px0 = pr.x - pr.z * 0.5f;
            float py0 = pr.y - pr.w * 0.5f;
            float px1 = pr.x + pr.z * 0.5f;
            float py1 = pr.y + pr.w * 0.5f;
            float ltx = fmaxf(bx0, px0);
            float lty = fmaxf(by0, py0);
            float rbx = fminf(bx1, px1);
            float rby = fminf(by1, py1);
            float wx = fmaxf(rbx - ltx, 0.0f);
            float wy = fmaxf(rby - lty, 0.0f);
            float inter = wx * wy;
            float ov = inter * __builtin_amdgcn_rcpf(marea + pr.z * pr.w - inter);
            if (ov > bv) { bv = ov; bi = p; }   // first-max (p ascending per lane)
        }
#pragma unroll
        for (int o = 32; o > 0; o >>= 1) {
            float v2 = __shfl_down(bv, o, 64);
            int   i2 = __shfl_down(bi, o, 64);
            if (v2 > bv || (v2 == bv && i2 < bi)) { bv = v2; bi = i2; }
        }
        if (lane == 0) cand[bk * M_ + m] = make_int2(__float_as_int(bv), bi);
    }
}

// ============ K2: fixup correction + hard-neg mining. grid = 128. ============
__global__ __launch_bounds__(NT) void mbox_loss_kernel(
    const float* __restrict__ plocs,
    const float* __restrict__ pscores,
    const float* __restrict__ boxes,
    const int*   __restrict__ labels,
    const float* __restrict__ priors,
    const unsigned char* __restrict__ objov,
    const unsigned short* __restrict__ bcew,
    const int2* __restrict__ cand,
    const float* __restrict__ pcf, const float* __restrict__ plc,
    const int* __restrict__ pnp,
    float* __restrict__ out,
    unsigned int* __restrict__ g_cnt,
    float* __restrict__ g_conf, float* __restrict__ g_loc, int* __restrict__ g_np)
{
    __shared__ float s_boxes[M_ * 4];
    __shared__ int   s_labels[M_];
    __shared__ int   s_po[M_];
    __shared__ int   s_fidx[M_];
    __shared__ float s_pf[2 * NW];
    __shared__ int   s_pi[NW];
    __shared__ int   s_cnt2[2][NW];
    __shared__ float s_scal[2];
    __shared__ int   s_npos;

    const int r = blockIdx.x;
    const int tid = threadIdx.x;
    const int lane = tid & 63;
    const int wid = tid >> 6;

    if (tid < M_ * 4) s_boxes[tid] = boxes[r * M_ * 4 + tid];
    if (tid >= 64 && tid < 64 + M_) s_labels[tid - 64] = labels[r * M_ + (tid - 64)];
    if (tid >= 128 && tid < 128 + M_) {
        int m = tid - 128;
        int2 c = cand[(r * 4) * M_ + m];
        float v = __int_as_float(c.x); int idx = c.y;
#pragma unroll
        for (int qq = 1; qq < 4; ++qq) {
            int2 c2 = cand[(r * 4 + qq) * M_ + m];
            float v2 = __int_as_float(c2.x);
            if (v2 > v) { v = v2; idx = c2.y; }   // strict >: earliest quarter wins ties
        }
        s_po[m] = idx;
    }
    __syncthreads();

    // ---- serial fixup correction (<=16 priors, last m wins on duplicates)
    if (tid == 0) {
        int   fidx[M_]; unsigned char fbyte[M_]; int fcnt = 0;
        int   dnp = 0; float dcp = 0.0f, dls = 0.0f;
        for (int m = 0; m < M_; ++m) {
            int idx = s_po[m];
            unsigned char byte = objov[(size_t)r * P_ + idx];
            int slot = -1;
            for (int j = 0; j < fcnt; ++j)
                if (fidx[j] == idx) { byte = fbyte[j]; slot = j; }
            bool oldpos = (byte & 0x80) != 0;
            int  oldobj = byte & 15;
            float4 pr = ((const float4*)priors)[idx];
            float4 pl = ((const float4*)plocs)[(size_t)r * P_ + idx];
            if (oldpos) {   // remove old pos contribution
                dcp -= bce3(pscores + ((size_t)r * P_ + idx) * 3, s_labels[oldobj]);
                float bx0 = s_boxes[oldobj*4+0], by0 = s_boxes[oldobj*4+1];
                float bx1 = s_boxes[oldobj*4+2], by1 = s_boxes[oldobj*4+3];
                float cx = (bx0+bx1)*0.5f, cy = (by0+by1)*0.5f;
                float w = bx1-bx0, hh = by1-by0;
                float g0 = (cx - pr.x) / (pr.z * 0.1f);
                float g1 = (cy - pr.y) / (pr.w * 0.1f);
                float g2 = logf(w / pr.z) * 5.0f;
                float g3 = logf(hh / pr.w) * 5.0f;
                dls -= fabsf(pl.x-g0)+fabsf(pl.y-g1)+fabsf(pl.z-g2)+fabsf(pl.w-g3);
                dnp--;
            }
            // add new pos contribution (obj = m)
            dcp += bce3(pscores + ((size_t)r * P_ + idx) * 3, s_labels[m]);
            {
                float bx0 = s_boxes[m*4+0], by0 = s_boxes[m*4+1];
                float bx1 = s_boxes[m*4+2], by1 = s_boxes[m*4+3];
                float cx = (bx0+bx1)*0.5f, cy = (by0+by1)*0.5f;
                float w = bx1-bx0, hh = by1-by0;
                float g0 = (cx - pr.x) / (pr.z * 0.1f);
                float g1 = (cy - pr.y) / (pr.w * 0.1f);
                float g2 = logf(w / pr.z) * 5.0f;
                float g3 = logf(hh / pr.w) * 5.0f;
                dls += fabsf(pl.x-g0)+fabsf(pl.y-g1)+fabsf(pl.z-g2)+fabsf(pl.w-g3);
            }
            dnp++;
            if (slot < 0) { fidx[fcnt] = idx; fbyte[fcnt] = (unsigned char)(0x80 | m); fcnt++; }
            else fbyte[slot] = (unsigned char)(0x80 | m);
        }
        float cp = dcp, lsx = dls; int np = dnp;
#pragma unroll
        for (int qq = 0; qq < 4; ++qq) {
            cp  += pcf[r * 4 + qq];
            lsx += plc[r * 4 + qq];
            np  += pnp[r * 4 + qq];
        }
        s_scal[0] = cp; s_scal[1] = lsx; s_npos = np;
#pragma unroll
        for (int j = 0; j < M_; ++j) s_fidx[j] = (j < fcnt) ? fidx[j] : -1;
    }
    __syncthreads();
    const int npos_row = s_npos;

    // ---- load neg bce (fp16 bits) and zero the fixed-up priors
    int fv_b[NP9];
#pragma unroll
    for (int i = 0; i < NP9; ++i) {
        int p = tid + i * NT;
        fv_b[i] = (p < P_) ? (int)bcew[(size_t)r * P_ + p] : 0;
#pragma unroll
        for (int j = 0; j < M_; ++j)
            if (s_fidx[j] == p) fv_b[i] = 0;
    }

    // ---- exact top-k over fp16 patterns: 15-step bisection, 1 barrier/iter
    int k = 3 * npos_row;
    if (k > P_) k = P_;
    float hard_sum = 0.0f;
    if (k > 0) {
        int lo = -1, hi = 0x7C00;   // invariant: cnt(lo)>=k, cnt(hi)<k
        for (int it = 0; it < 15; ++it) {
            int mid = (lo + hi) >> 1;
            int c = 0;
#pragma unroll
            for (int i = 0; i < NP9; ++i) c += (fv_b[i] > mid) ? 1 : 0;
            c = wred_sum_i(c);
            if (lane == 0) s_cnt2[it & 1][wid] = c;
            __syncthreads();
            int cnt = 0;
#pragma unroll
            for (int w = 0; w < NW; ++w) cnt += s_cnt2[it & 1][w];
            if (cnt < k) hi = mid; else lo = mid;
        }
        int tb = hi;                               // k-th largest fp16 pattern
        float tval = __half2float(__ushort_as_half((unsigned short)tb));
        float lsum = 0.0f; int lcnt = 0;
#pragma unroll
        for (int i = 0; i < NP9; ++i) {
            if (fv_b[i] > tb) {
                lsum += __half2float(__ushort_as_half((unsigned short)fv_b[i]));
                lcnt++;
            }
        }
        lsum = wred_sum_f(lsum);
        lcnt = wred_sum_i(lcnt);
        if (lane == 0) { s_pf[wid] = lsum; s_pi[wid] = lcnt; }
        __syncthreads();
        if (tid == 0) {
            float sv = 0.0f; int sc2 = 0;
#pragma unroll
            for (int w = 0; w < NW; ++w) { sv += s_pf[w]; sc2 += s_pi[w]; }
            hard_sum = sv + (float)(k - sc2) * tval;
        }
    }

    // ---- finalize
    if (tid == 0) {
        float conf_row = s_scal[0] + hard_sum;
        float loc_row  = s_scal[1];
        out[3 + r] = (float)npos_row;
        atomicAdd(g_conf, conf_row);
        atomicAdd(g_loc,  loc_row);
        atomicAdd(g_np,   npos_row);
        __threadfence();
        unsigned int done = atomicAdd(g_cnt, 1u);
        if (done == B_ - 1) {
            float ct = atomicAdd(g_conf, 0.0f);
            float lt = atomicAdd(g_loc,  0.0f);
            int   np = atomicAdd(g_np,   0);
            float npt = (float)np;
            float conf_loss = ct / (1e-10f + npt);
            float loc_loss = (np > 0) ? lt / (4.0f * fmaxf(npt, 1.0f)) : 0.0f;
            out[0] = conf_loss + loc_loss;   // ALPHA = 1
            out[1] = conf_loss;
            out[2] = loc_loss;
        }
    }
}

extern "C" void kernel_launch(void* const* d_in, const int* in_sizes, int n_in,
                              void* d_out, int out_size, void* d_ws, size_t ws_size,
                              hipStream_t stream) {
    const float* plocs   = (const float*)d_in[0];
    const float* pscores = (const float*)d_in[1];
    const float* boxes   = (const float*)d_in[2];
    const int*   labels  = (const int*)  d_in[3];
    const float* priors  = (const float*)d_in[4];
    float* out = (float*)d_out;

    // ws layout (~3.5 MB total):
    //   [0,16)        g_cnt, g_conf, g_loc, g_np
    //   [64, +2K)     pcf float[512]
    //   [2112, +2K)   plc float[512]
    //   [4160, +2K)   pnp int[512]
    //   [8192, +64K)  cand int2[512*16]
    //   [73728, +1117696)  objov bytes
    //   [1191424, +2235392) bcew fp16
    char* ws = (char*)d_ws;
    unsigned int* g_cnt  = (unsigned int*)ws;
    float*        g_conf = (float*)(ws + 4);
    float*        g_loc  = (float*)(ws + 8);
    int*          g_np   = (int*)(ws + 12);
    float*        pcf    = (float*)(ws + 64);
    float*        plc    = (float*)(ws + 2112);
    int*          pnp    = (int*)(ws + 4160);
    int2*         cand   = (int2*)(ws + 8192);
    unsigned char* objov = (unsigned char*)(ws + 73728);
    unsigned short* bcew = (unsigned short*)(ws + 73728 + (size_t)B_ * P_);

    mbox_match_kernel<<<4 * B_, NT, 0, stream>>>(plocs, pscores, boxes, labels, priors,
                                                 objov, bcew, cand, pcf, plc, pnp,
                                                 (unsigned int*)ws);
    mbox_loss_kernel<<<B_, NT, 0, stream>>>(plocs, pscores, boxes, labels, priors,
                                            objov, bcew, cand, pcf, plc, pnp,
                                            out, g_cnt, g_conf, g_loc, g_np);
}

// Round 11
// 145.482 us; speedup vs baseline: 1.3407x; 1.3407x over previous
//
#include <hip/hip_runtime.h>
#include <hip/hip_fp16.h>
#include <cstdint>
#include <cmath>

#define B_ 128
#define P_ 8732
#define QU_ 2183        // P_ / 4 exactly
#define M_ 16
#define NT 1024
#define NW 16           // waves per block == M_
#define NP9 9           // ceil(P_/NT)

__device__ __forceinline__ float softplusf(float x) {
    return fmaxf(x, 0.0f) + log1pf(expf(-fabsf(x)));
}

__device__ __forceinline__ float wred_sum_f(float v) {
#pragma unroll
    for (int o = 32; o > 0; o >>= 1) v += __shfl_down(v, o, 64);
    return v;
}
__device__ __forceinline__ int wred_sum_i(int v) {
#pragma unroll
    for (int o = 32; o > 0; o >>= 1) v += __shfl_down(v, o, 64);
    return v;
}

__device__ __forceinline__ float bce3(const float* sc, int lab) {
    float x0 = sc[0], x1 = sc[1], x2 = sc[2];
    float t0 = (lab == 0) ? 1.0f : 0.0f;
    float t1 = (lab == 1 || lab == 3) ? 1.0f : 0.0f;
    float t2 = (lab == 2 || lab == 3) ? 1.0f : 0.0f;
    return (softplusf(x0) - x0*t0) + (softplusf(x1) - x1*t1) + (softplusf(x2) - x2*t2);
}

// ============ K1: match + BCE/L1 (no-fixup assumption). grid = 512. ==========
__global__ __launch_bounds__(NT) void mbox_match_kernel(
    const float* __restrict__ plocs,   // (B,P,4)
    const float* __restrict__ pscores, // (B,P,3)
    const float* __restrict__ boxes,   // (B,M,4) xyxy
    const int*   __restrict__ labels,  // (B,M)
    const float* __restrict__ priors,  // (P,4) cxcy
    unsigned char* __restrict__ objov,
    unsigned short* __restrict__ bcew,
    int2* __restrict__ cand,
    float* __restrict__ pcf, float* __restrict__ plc, int* __restrict__ pnp,
    unsigned int* __restrict__ gz)     // 4 words to zero (g_cnt,g_conf,g_loc,g_np)
{
    __shared__ float s_boxes[M_ * 4];
    __shared__ float s_area[M_];
    __shared__ int   s_labels[M_];
    __shared__ float s_pf[2 * NW];
    __shared__ int   s_pi[NW];

    const int bk = blockIdx.x;
    const int r  = bk >> 2;
    const int q  = bk & 3;
    const int tid = threadIdx.x;
    const int lane = tid & 63;
    const int wid = tid >> 6;

    if (bk == 0 && tid < 4) gz[tid] = 0u;   // zero global accumulators for K2

    if (tid < M_ * 4) s_boxes[tid] = boxes[r * M_ * 4 + tid];
    if (tid >= 64 && tid < 64 + M_) s_labels[tid - 64] = labels[r * M_ + (tid - 64)];
    __syncthreads();
    if (tid < M_) {
        float x0 = s_boxes[tid*4+0], y0 = s_boxes[tid*4+1];
        float x1 = s_boxes[tid*4+2], y1 = s_boxes[tid*4+3];
        s_area[tid] = (x1 - x0) * (y1 - y0);
    }
    __syncthreads();

    const int p0 = q * QU_;

    // ---- Phase A+D fused: per-prior best object, then bce/l1 with that match
    int np = 0; float cp = 0.0f, ls = 0.0f;
    for (int p = p0 + tid; p < p0 + QU_; p += NT) {
        float4 pr = ((const float4*)priors)[p];
        float px0 = pr.x - pr.z * 0.5f;
        float py0 = pr.y - pr.w * 0.5f;
        float px1 = pr.x + pr.z * 0.5f;
        float py1 = pr.y + pr.w * 0.5f;
        float parea = pr.z * pr.w;
        float bestv = -1.0f; int besti = 0;
#pragma unroll
        for (int m = 0; m < M_; ++m) {
            float ltx = fmaxf(s_boxes[m*4+0], px0);
            float lty = fmaxf(s_boxes[m*4+1], py0);
            float rbx = fminf(s_boxes[m*4+2], px1);
            float rby = fminf(s_boxes[m*4+3], py1);
            float wx = fmaxf(rbx - ltx, 0.0f);
            float wy = fmaxf(rby - lty, 0.0f);
            float inter = wx * wy;
            float ov = inter * __builtin_amdgcn_rcpf(s_area[m] + parea - inter);
            if (ov > bestv) { bestv = ov; besti = m; }       // first-max over m
        }
        bool pos = bestv >= 0.5f;
        objov[(size_t)r * P_ + p] = (unsigned char)(besti | (pos ? 0x80 : 0));

        int lab = pos ? s_labels[besti] : 0;
        float bce = bce3(pscores + ((size_t)r * P_ + p) * 3, lab);
        float hb = 0.0f;
        if (pos) {
            np++; cp += bce;
            float bx0 = s_boxes[besti*4+0], by0 = s_boxes[besti*4+1];
            float bx1 = s_boxes[besti*4+2], by1 = s_boxes[besti*4+3];
            float cx = (bx0 + bx1) * 0.5f, cy = (by0 + by1) * 0.5f;
            float w = bx1 - bx0, hh = by1 - by0;
            float g0 = (cx - pr.x) / (pr.z * 0.1f);
            float g1 = (cy - pr.y) / (pr.w * 0.1f);
            float g2 = logf(w / pr.z) * 5.0f;
            float g3 = logf(hh / pr.w) * 5.0f;
            float4 pl = ((const float4*)plocs)[(size_t)r * P_ + p];
            ls += fabsf(pl.x - g0) + fabsf(pl.y - g1) + fabsf(pl.z - g2) + fabsf(pl.w - g3);
        } else {
            hb = bce;
        }
        bcew[(size_t)r * P_ + p] = __half_as_ushort(__float2half(hb));
    }

    // ---- reduce quarter partials
    {
        float cpr = wred_sum_f(cp);
        float lsr = wred_sum_f(ls);
        int   npr = wred_sum_i(np);
        if (lane == 0) { s_pf[wid] = cpr; s_pf[NW + wid] = lsr; s_pi[wid] = npr; }
    }
    __syncthreads();
    if (tid == 0) {
        float c2 = 0.0f, l2 = 0.0f; int n2 = 0;
#pragma unroll
        for (int w = 0; w < NW; ++w) { c2 += s_pf[w]; l2 += s_pf[NW + w]; n2 += s_pi[w]; }
        pcf[bk] = c2; plc[bk] = l2; pnp[bk] = n2;
    }

    // ---- Phase B: one WAVE per object, wave-argmax over the quarter
    {
        const int m = wid;
        float bx0 = s_boxes[m*4+0], by0 = s_boxes[m*4+1];
        float bx1 = s_boxes[m*4+2], by1 = s_boxes[m*4+3];
        float marea = s_area[m];
        float bv = -1.0f; int bi = 0x7FFFFFFF;
        for (int p = p0 + lane; p < p0 + QU_; p += 64) {
            float4 pr = ((const float4*)priors)[p];
            float px0 = pr.x - pr.z * 0.5f;
            float py0 = pr.y - pr.w * 0.5f;
            float px1 = pr.x + pr.z * 0.5f;
            float py1 = pr.y + pr.w * 0.5f;
            float ltx = fmaxf(bx0, px0);
            float lty = fmaxf(by0, py0);
            float rbx = fminf(bx1, px1);
            float rby = fminf(by1, py1);
            float wx = fmaxf(rbx - ltx, 0.0f);
            float wy = fmaxf(rby - lty, 0.0f);
            float inter = wx * wy;
            float ov = inter * __builtin_amdgcn_rcpf(marea + pr.z * pr.w - inter);
            if (ov > bv) { bv = ov; bi = p; }   // first-max (p ascending per lane)
        }
#pragma unroll
        for (int o = 32; o > 0; o >>= 1) {
            float v2 = __shfl_down(bv, o, 64);
            int   i2 = __shfl_down(bi, o, 64);
            if (v2 > bv || (v2 == bv && i2 < bi)) { bv = v2; bi = i2; }
        }
        if (lane == 0) cand[bk * M_ + m] = make_int2(__float_as_int(bv), bi);
    }
}

// ============ K2: parallel fixup correction + hard-neg mining. grid = 128. ===
__global__ __launch_bounds__(NT) void mbox_loss_kernel(
    const float* __restrict__ plocs,
    const float* __restrict__ pscores,
    const float* __restrict__ boxes,
    const int*   __restrict__ labels,
    const float* __restrict__ priors,
    const unsigned char* __restrict__ objov,
    const unsigned short* __restrict__ bcew,
    const int2* __restrict__ cand,
    const float* __restrict__ pcf, const float* __restrict__ plc,
    const int* __restrict__ pnp,
    float* __restrict__ out,
    unsigned int* __restrict__ g_cnt,
    float* __restrict__ g_conf, float* __restrict__ g_loc, int* __restrict__ g_np)
{
    __shared__ float s_boxes[M_ * 4];
    __shared__ int   s_labels[M_];
    __shared__ int   s_po[M_];
    __shared__ float s_pf[2 * NW];
    __shared__ int   s_pi[NW];
    __shared__ int   s_cnt2[2][NW];
    __shared__ float s_scal[2];
    __shared__ int   s_npos;

    const int r = blockIdx.x;
    const int tid = threadIdx.x;
    const int lane = tid & 63;
    const int wid = tid >> 6;

    if (tid < M_ * 4) s_boxes[tid] = boxes[r * M_ * 4 + tid];
    if (tid >= 64 && tid < 64 + M_) s_labels[tid - 64] = labels[r * M_ + (tid - 64)];
    if (tid >= 128 && tid < 128 + M_) {
        int m = tid - 128;
        int2 c = cand[(r * 4) * M_ + m];
        float v = __int_as_float(c.x); int idx = c.y;
#pragma unroll
        for (int qq = 1; qq < 4; ++qq) {
            int2 c2 = cand[(r * 4 + qq) * M_ + m];
            float v2 = __int_as_float(c2.x);
            if (v2 > v) { v = v2; idx = c2.y; }   // strict >: earliest quarter wins ties
        }
        s_po[m] = idx;
    }
    __syncthreads();

    // ---- load neg bce early (independent of fixup -> latency overlap)
    int fv_b[NP9];
#pragma unroll
    for (int i = 0; i < NP9; ++i) {
        int p = tid + i * NT;
        fv_b[i] = (p < P_) ? (int)bcew[(size_t)r * P_ + p] : 0;
    }

    // ---- PARALLEL fixup: lane m of wave 0 owns object m; "last m wins" =>
    //      owner iff no m' > m maps to the same prior. Register-only.
    if (wid == 0) {
        float dcp = 0.0f, dls = 0.0f; int dnp = 0;
        if (lane < M_) {
            const int m = lane;
            const int idx = s_po[m];
            bool owner = true;
            for (int m2 = m + 1; m2 < M_; ++m2)
                if (s_po[m2] == idx) owner = false;
            if (owner) {
                unsigned char byte = objov[(size_t)r * P_ + idx];
                bool oldpos = (byte & 0x80) != 0;
                int  oldobj = byte & 15;
                const float* sc = pscores + ((size_t)r * P_ + idx) * 3;
                float x0 = sc[0], x1 = sc[1], x2 = sc[2];
                float S = softplusf(x0) + softplusf(x1) + softplusf(x2);
                float4 pr = ((const float4*)priors)[idx];
                float4 pl = ((const float4*)plocs)[(size_t)r * P_ + idx];
                // bce(lab) = S - x.t(lab)
                {
                    int lab = s_labels[m];
                    float t0 = (lab == 0) ? 1.0f : 0.0f;
                    float t1 = (lab == 1 || lab == 3) ? 1.0f : 0.0f;
                    float t2 = (lab == 2 || lab == 3) ? 1.0f : 0.0f;
                    dcp += S - (x0*t0 + x1*t1 + x2*t2);
                    float bx0 = s_boxes[m*4+0], by0 = s_boxes[m*4+1];
                    float bx1 = s_boxes[m*4+2], by1 = s_boxes[m*4+3];
                    float cx = (bx0+bx1)*0.5f, cy = (by0+by1)*0.5f;
                    float w = bx1-bx0, hh = by1-by0;
                    float g0 = (cx - pr.x) / (pr.z * 0.1f);
                    float g1 = (cy - pr.y) / (pr.w * 0.1f);
                    float g2 = logf(w / pr.z) * 5.0f;
                    float g3 = logf(hh / pr.w) * 5.0f;
                    dls += fabsf(pl.x-g0)+fabsf(pl.y-g1)+fabsf(pl.z-g2)+fabsf(pl.w-g3);
                    dnp += 1;
                }
                if (oldpos) {
                    int lab = s_labels[oldobj];
                    float t0 = (lab == 0) ? 1.0f : 0.0f;
                    float t1 = (lab == 1 || lab == 3) ? 1.0f : 0.0f;
                    float t2 = (lab == 2 || lab == 3) ? 1.0f : 0.0f;
                    dcp -= S - (x0*t0 + x1*t1 + x2*t2);
                    float bx0 = s_boxes[oldobj*4+0], by0 = s_boxes[oldobj*4+1];
                    float bx1 = s_boxes[oldobj*4+2], by1 = s_boxes[oldobj*4+3];
                    float cx = (bx0+bx1)*0.5f, cy = (by0+by1)*0.5f;
                    float w = bx1-bx0, hh = by1-by0;
                    float g0 = (cx - pr.x) / (pr.z * 0.1f);
                    float g1 = (cy - pr.y) / (pr.w * 0.1f);
                    float g2 = logf(w / pr.z) * 5.0f;
                    float g3 = logf(hh / pr.w) * 5.0f;
                    dls -= fabsf(pl.x-g0)+fabsf(pl.y-g1)+fabsf(pl.z-g2)+fabsf(pl.w-g3);
                    dnp -= 1;
                }
            }
        }
        dcp = wred_sum_f(dcp);
        dls = wred_sum_f(dls);
        dnp = wred_sum_i(dnp);
        if (lane == 0) {
            float cp = dcp, lsx = dls; int np = dnp;
#pragma unroll
            for (int qq = 0; qq < 4; ++qq) {
                cp  += pcf[r * 4 + qq];
                lsx += plc[r * 4 + qq];
                np  += pnp[r * 4 + qq];
            }
            s_scal[0] = cp; s_scal[1] = lsx; s_npos = np;
        }
    }
    __syncthreads();
    const int npos_row = s_npos;

    // ---- zero fixed-up priors in fv_b (every s_po entry ends positive)
#pragma unroll
    for (int i = 0; i < NP9; ++i) {
        int p = tid + i * NT;
#pragma unroll
        for (int j = 0; j < M_; ++j)
            if (s_po[j] == p) fv_b[i] = 0;
    }

    // ---- exact top-k over fp16 patterns: 15-step bisection, 1 barrier/iter
    int k = 3 * npos_row;
    if (k > P_) k = P_;
    float hard_sum = 0.0f;
    if (k > 0) {
        int lo = -1, hi = 0x7C00;   // invariant: cnt(lo)>=k, cnt(hi)<k
        for (int it = 0; it < 15; ++it) {
            int mid = (lo + hi) >> 1;
            int c = 0;
#pragma unroll
            for (int i = 0; i < NP9; ++i) c += (fv_b[i] > mid) ? 1 : 0;
            c = wred_sum_i(c);
            if (lane == 0) s_cnt2[it & 1][wid] = c;
            __syncthreads();
            int cnt = 0;
#pragma unroll
            for (int w = 0; w < NW; ++w) cnt += s_cnt2[it & 1][w];
            if (cnt < k) hi = mid; else lo = mid;
        }
        int tb = hi;                               // k-th largest fp16 pattern
        float tval = __half2float(__ushort_as_half((unsigned short)tb));
        float lsum = 0.0f; int lcnt = 0;
#pragma unroll
        for (int i = 0; i < NP9; ++i) {
            if (fv_b[i] > tb) {
                lsum += __half2float(__ushort_as_half((unsigned short)fv_b[i]));
                lcnt++;
            }
        }
        lsum = wred_sum_f(lsum);
        lcnt = wred_sum_i(lcnt);
        if (lane == 0) { s_pf[wid] = lsum; s_pi[wid] = lcnt; }
        __syncthreads();
        if (tid == 0) {
            float sv = 0.0f; int sc2 = 0;
#pragma unroll
            for (int w = 0; w < NW; ++w) { sv += s_pf[w]; sc2 += s_pi[w]; }
            hard_sum = sv + (float)(k - sc2) * tval;
        }
    }

    // ---- finalize
    if (tid == 0) {
        float conf_row = s_scal[0] + hard_sum;
        float loc_row  = s_scal[1];
        out[3 + r] = (float)npos_row;
        atomicAdd(g_conf, conf_row);
        atomicAdd(g_loc,  loc_row);
        atomicAdd(g_np,   npos_row);
        __threadfence();
        unsigned int done = atomicAdd(g_cnt, 1u);
        if (done == B_ - 1) {
            float ct = atomicAdd(g_conf, 0.0f);
            float lt = atomicAdd(g_loc,  0.0f);
            int   np = atomicAdd(g_np,   0);
            float npt = (float)np;
            float conf_loss = ct / (1e-10f + npt);
            float loc_loss = (np > 0) ? lt / (4.0f * fmaxf(npt, 1.0f)) : 0.0f;
            out[0] = conf_loss + loc_loss;   // ALPHA = 1
            out[1] = conf_loss;
            out[2] = loc_loss;
        }
    }
}

extern "C" void kernel_launch(void* const* d_in, const int* in_sizes, int n_in,
                              void* d_out, int out_size, void* d_ws, size_t ws_size,
                              hipStream_t stream) {
    const float* plocs   = (const float*)d_in[0];
    const float* pscores = (const float*)d_in[1];
    const float* boxes   = (const float*)d_in[2];
    const int*   labels  = (const int*)  d_in[3];
    const float* priors  = (const float*)d_in[4];
    float* out = (float*)d_out;

    // ws layout (~3.5 MB total):
    //   [0,16)        g_cnt, g_conf, g_loc, g_np
    //   [64, +2K)     pcf float[512]
    //   [2112, +2K)   plc float[512]
    //   [4160, +2K)   pnp int[512]
    //   [8192, +64K)  cand int2[512*16]
    //   [73728, +1117696)  objov bytes
    //   [1191424, +2235392) bcew fp16
    char* ws = (char*)d_ws;
    unsigned int* g_cnt  = (unsigned int*)ws;
    float*        g_conf = (float*)(ws + 4);
    float*        g_loc  = (float*)(ws + 8);
    int*          g_np   = (int*)(ws + 12);
    float*        pcf    = (float*)(ws + 64);
    float*        plc    = (float*)(ws + 2112);
    int*          pnp    = (int*)(ws + 4160);
    int2*         cand   = (int2*)(ws + 8192);
    unsigned char* objov = (unsigned char*)(ws + 73728);
    unsigned short* bcew = (unsigned short*)(ws + 73728 + (size_t)B_ * P_);

    mbox_match_kernel<<<4 * B_, NT, 0, stream>>>(plocs, pscores, boxes, labels, priors,
                                                 objov, bcew, cand, pcf, plc, pnp,
                                                 (unsigned int*)ws);
    mbox_loss_kernel<<<B_, NT, 0, stream>>>(plocs, pscores, boxes, labels, priors,
                                            objov, bcew, cand, pcf, plc, pnp,
                                            out, g_cnt, g_conf, g_loc, g_np);
}

// Round 12
// 136.348 us; speedup vs baseline: 1.4305x; 1.0670x over previous
//
#include <hip/hip_runtime.h>
#include <hip/hip_fp16.h>
#include <cstdint>
#include <cmath>

#define B_ 128
#define P_ 8732
#define QU_ 2183        // P_ / 4 exactly
#define M_ 16
#define NT 1024
#define NW 16           // waves per block == M_
#define NP9 9           // ceil(P_/NT)

__device__ __forceinline__ float softplusf(float x) {
    return fmaxf(x, 0.0f) + log1pf(expf(-fabsf(x)));
}

__device__ __forceinline__ float wred_sum_f(float v) {
#pragma unroll
    for (int o = 32; o > 0; o >>= 1) v += __shfl_down(v, o, 64);
    return v;
}
__device__ __forceinline__ int wred_sum_i(int v) {
#pragma unroll
    for (int o = 32; o > 0; o >>= 1) v += __shfl_down(v, o, 64);
    return v;
}

// ============ K1: fused match (A+B via LDS atomic-max) + BCE/L1. grid=512. ===
// block bk: row r = bk>>2, quarter q = bk&3. Wave m owns object m: computes
// ov(m,p) ONCE per prior; per-p argmax over m goes through a packed u64
// LDS atomicMax ((bits(ov)<<4)|(15-m): exact lexicographic (ov, lowest-m)),
// per-m argmax over p is a wave shuffle reduce.
__global__ __launch_bounds__(NT) void mbox_match_kernel(
    const float* __restrict__ plocs,   // (B,P,4)
    const float* __restrict__ pscores, // (B,P,3)
    const float* __restrict__ boxes,   // (B,M,4) xyxy
    const int*   __restrict__ labels,  // (B,M)
    const float* __restrict__ priors,  // (P,4) cxcy
    unsigned char* __restrict__ objov,
    unsigned short* __restrict__ bcew,
    int2* __restrict__ cand,
    float* __restrict__ pcf, float* __restrict__ plc, int* __restrict__ pnp,
    unsigned int* __restrict__ gz)     // 4 words to zero (g_cnt,g_conf,g_loc,g_np)
{
    __shared__ unsigned long long s_ovp[QU_];   // packed (ov_bits<<4)|(15-m)
    __shared__ float s_boxes[M_ * 4];
    __shared__ float s_area[M_];
    __shared__ int   s_labels[M_];
    __shared__ float s_pf[2 * NW];
    __shared__ int   s_pi[NW];

    const int bk = blockIdx.x;
    const int r  = bk >> 2;
    const int q  = bk & 3;
    const int tid = threadIdx.x;
    const int lane = tid & 63;
    const int wid = tid >> 6;

    if (bk == 0 && tid < 4) gz[tid] = 0u;   // zero global accumulators for K2

    if (tid < M_ * 4) s_boxes[tid] = boxes[r * M_ * 4 + tid];
    if (tid >= 64 && tid < 64 + M_) s_labels[tid - 64] = labels[r * M_ + (tid - 64)];
    for (int i = tid; i < QU_; i += NT) s_ovp[i] = 0ull;
    __syncthreads();
    if (tid < M_) {
        float x0 = s_boxes[tid*4+0], y0 = s_boxes[tid*4+1];
        float x1 = s_boxes[tid*4+2], y1 = s_boxes[tid*4+3];
        s_area[tid] = (x1 - x0) * (y1 - y0);
    }
    __syncthreads();

    const int p0 = q * QU_;

    // ---- Phase A+B fused: wave m scans the quarter once for object m
    {
        const int m = wid;
        const float bx0 = s_boxes[m*4+0], by0 = s_boxes[m*4+1];
        const float bx1 = s_boxes[m*4+2], by1 = s_boxes[m*4+3];
        const float marea = s_area[m];
        const unsigned long long tag = (unsigned long long)(15 - m);
        float bv = -1.0f; int bi = 0x7FFFFFFF;
        for (int p = p0 + lane; p < p0 + QU_; p += 64) {
            float4 pr = ((const float4*)priors)[p];
            float px0 = pr.x - pr.z * 0.5f;
            float py0 = pr.y - pr.w * 0.5f;
            float px1 = pr.x + pr.z * 0.5f;
            float py1 = pr.y + pr.w * 0.5f;
            float ltx = fmaxf(bx0, px0);
            float lty = fmaxf(by0, py0);
            float rbx = fminf(bx1, px1);
            float rby = fminf(by1, py1);
            float wx = fmaxf(rbx - ltx, 0.0f);
            float wy = fmaxf(rby - lty, 0.0f);
            float inter = wx * wy;
            float ov = inter * __builtin_amdgcn_rcpf(marea + pr.z * pr.w - inter);
            unsigned long long pk =
                ((unsigned long long)__float_as_uint(ov) << 4) | tag;
            atomicMax(&s_ovp[p - p0], pk);
            if (ov > bv) { bv = ov; bi = p; }   // first-max (p ascending per lane)
        }
#pragma unroll
        for (int o = 32; o > 0; o >>= 1) {
            float v2 = __shfl_down(bv, o, 64);
            int   i2 = __shfl_down(bi, o, 64);
            if (v2 > bv || (v2 == bv && i2 < bi)) { bv = v2; bi = i2; }
        }
        if (lane == 0) cand[bk * M_ + m] = make_int2(__float_as_int(bv), bi);
    }
    __syncthreads();

    // ---- Phase D: unpack per-prior best, bce/l1, partials
    int np = 0; float cp = 0.0f, ls = 0.0f;
    for (int p = p0 + tid; p < p0 + QU_; p += NT) {
        unsigned long long u = s_ovp[p - p0];
        int   besti = 15 - (int)(u & 15ull);
        float bestv = __uint_as_float((unsigned int)(u >> 4));
        bool pos = bestv >= 0.5f;
        objov[(size_t)r * P_ + p] = (unsigned char)(besti | (pos ? 0x80 : 0));

        const float* sc = pscores + ((size_t)r * P_ + p) * 3;
        float x0 = sc[0], x1 = sc[1], x2 = sc[2];
        int lab = pos ? s_labels[besti] : 0;
        float t0 = (lab == 0) ? 1.0f : 0.0f;
        float t1 = (lab == 1 || lab == 3) ? 1.0f : 0.0f;
        float t2 = (lab == 2 || lab == 3) ? 1.0f : 0.0f;
        float bce = (softplusf(x0) - x0*t0) + (softplusf(x1) - x1*t1) + (softplusf(x2) - x2*t2);
        float hb = 0.0f;
        if (pos) {
            np++; cp += bce;
            float4 pr = ((const float4*)priors)[p];
            float bx0 = s_boxes[besti*4+0], by0 = s_boxes[besti*4+1];
            float bx1 = s_boxes[besti*4+2], by1 = s_boxes[besti*4+3];
            float cx = (bx0 + bx1) * 0.5f, cy = (by0 + by1) * 0.5f;
            float w = bx1 - bx0, hh = by1 - by0;
            float g0 = (cx - pr.x) / (pr.z * 0.1f);
            float g1 = (cy - pr.y) / (pr.w * 0.1f);
            float g2 = logf(w / pr.z) * 5.0f;
            float g3 = logf(hh / pr.w) * 5.0f;
            float4 pl = ((const float4*)plocs)[(size_t)r * P_ + p];
            ls += fabsf(pl.x - g0) + fabsf(pl.y - g1) + fabsf(pl.z - g2) + fabsf(pl.w - g3);
        } else {
            hb = bce;
        }
        bcew[(size_t)r * P_ + p] = __half_as_ushort(__float2half(hb));
    }

    // ---- reduce quarter partials
    {
        float cpr = wred_sum_f(cp);
        float lsr = wred_sum_f(ls);
        int   npr = wred_sum_i(np);
        if (lane == 0) { s_pf[wid] = cpr; s_pf[NW + wid] = lsr; s_pi[wid] = npr; }
    }
    __syncthreads();
    if (tid == 0) {
        float c2 = 0.0f, l2 = 0.0f; int n2 = 0;
#pragma unroll
        for (int w = 0; w < NW; ++w) { c2 += s_pf[w]; l2 += s_pf[NW + w]; n2 += s_pi[w]; }
        pcf[bk] = c2; plc[bk] = l2; pnp[bk] = n2;
    }
}

// ============ K2: parallel fixup correction + hard-neg mining. grid = 128. ===
__global__ __launch_bounds__(NT) void mbox_loss_kernel(
    const float* __restrict__ plocs,
    const float* __restrict__ pscores,
    const float* __restrict__ boxes,
    const int*   __restrict__ labels,
    const float* __restrict__ priors,
    const unsigned char* __restrict__ objov,
    const unsigned short* __restrict__ bcew,
    const int2* __restrict__ cand,
    const float* __restrict__ pcf, const float* __restrict__ plc,
    const int* __restrict__ pnp,
    float* __restrict__ out,
    unsigned int* __restrict__ g_cnt,
    float* __restrict__ g_conf, float* __restrict__ g_loc, int* __restrict__ g_np)
{
    __shared__ float s_boxes[M_ * 4];
    __shared__ int   s_labels[M_];
    __shared__ int   s_po[M_];
    __shared__ float s_pf[2 * NW];
    __shared__ int   s_pi[NW];
    __shared__ int   s_cnt2[2][NW];
    __shared__ float s_scal[2];
    __shared__ int   s_npos;

    const int r = blockIdx.x;
    const int tid = threadIdx.x;
    const int lane = tid & 63;
    const int wid = tid >> 6;

    if (tid < M_ * 4) s_boxes[tid] = boxes[r * M_ * 4 + tid];
    if (tid >= 64 && tid < 64 + M_) s_labels[tid - 64] = labels[r * M_ + (tid - 64)];
    if (tid >= 128 && tid < 128 + M_) {
        int m = tid - 128;
        int2 c = cand[(r * 4) * M_ + m];
        float v = __int_as_float(c.x); int idx = c.y;
#pragma unroll
        for (int qq = 1; qq < 4; ++qq) {
            int2 c2 = cand[(r * 4 + qq) * M_ + m];
            float v2 = __int_as_float(c2.x);
            if (v2 > v) { v = v2; idx = c2.y; }   // strict >: earliest quarter wins ties
        }
        s_po[m] = idx;
    }
    __syncthreads();

    // ---- load neg bce early (independent of fixup -> latency overlap)
    int fv_b[NP9];
#pragma unroll
    for (int i = 0; i < NP9; ++i) {
        int p = tid + i * NT;
        fv_b[i] = (p < P_) ? (int)bcew[(size_t)r * P_ + p] : 0;
    }

    // ---- PARALLEL fixup: lane m of wave 0 owns object m; "last m wins" =>
    //      owner iff no m' > m maps to the same prior. Register-only.
    if (wid == 0) {
        float dcp = 0.0f, dls = 0.0f; int dnp = 0;
        if (lane < M_) {
            const int m = lane;
            const int idx = s_po[m];
            bool owner = true;
            for (int m2 = m + 1; m2 < M_; ++m2)
                if (s_po[m2] == idx) owner = false;
            if (owner) {
                unsigned char byte = objov[(size_t)r * P_ + idx];
                bool oldpos = (byte & 0x80) != 0;
                int  oldobj = byte & 15;
                const float* sc = pscores + ((size_t)r * P_ + idx) * 3;
                float x0 = sc[0], x1 = sc[1], x2 = sc[2];
                float S = softplusf(x0) + softplusf(x1) + softplusf(x2);
                float4 pr = ((const float4*)priors)[idx];
                float4 pl = ((const float4*)plocs)[(size_t)r * P_ + idx];
                {
                    int lab = s_labels[m];
                    float t0 = (lab == 0) ? 1.0f : 0.0f;
                    float t1 = (lab == 1 || lab == 3) ? 1.0f : 0.0f;
                    float t2 = (lab == 2 || lab == 3) ? 1.0f : 0.0f;
                    dcp += S - (x0*t0 + x1*t1 + x2*t2);
                    float bx0 = s_boxes[m*4+0], by0 = s_boxes[m*4+1];
                    float bx1 = s_boxes[m*4+2], by1 = s_boxes[m*4+3];
                    float cx = (bx0+bx1)*0.5f, cy = (by0+by1)*0.5f;
                    float w = bx1-bx0, hh = by1-by0;
                    float g0 = (cx - pr.x) / (pr.z * 0.1f);
                    float g1 = (cy - pr.y) / (pr.w * 0.1f);
                    float g2 = logf(w / pr.z) * 5.0f;
                    float g3 = logf(hh / pr.w) * 5.0f;
                    dls += fabsf(pl.x-g0)+fabsf(pl.y-g1)+fabsf(pl.z-g2)+fabsf(pl.w-g3);
                    dnp += 1;
                }
                if (oldpos) {
                    int lab = s_labels[oldobj];
                    float t0 = (lab == 0) ? 1.0f : 0.0f;
                    float t1 = (lab == 1 || lab == 3) ? 1.0f : 0.0f;
                    float t2 = (lab == 2 || lab == 3) ? 1.0f : 0.0f;
                    dcp -= S - (x0*t0 + x1*t1 + x2*t2);
                    float bx0 = s_boxes[oldobj*4+0], by0 = s_boxes[oldobj*4+1];
                    float bx1 = s_boxes[oldobj*4+2], by1 = s_boxes[oldobj*4+3];
                    float cx = (bx0+bx1)*0.5f, cy = (by0+by1)*0.5f;
                    float w = bx1-bx0, hh = by1-by0;
                    float g0 = (cx - pr.x) / (pr.z * 0.1f);
                    float g1 = (cy - pr.y) / (pr.w * 0.1f);
                    float g2 = logf(w / pr.z) * 5.0f;
                    float g3 = logf(hh / pr.w) * 5.0f;
                    dls -= fabsf(pl.x-g0)+fabsf(pl.y-g1)+fabsf(pl.z-g2)+fabsf(pl.w-g3);
                    dnp -= 1;
                }
            }
        }
        dcp = wred_sum_f(dcp);
        dls = wred_sum_f(dls);
        dnp = wred_sum_i(dnp);
        if (lane == 0) {
            float cp = dcp, lsx = dls; int np = dnp;
#pragma unroll
            for (int qq = 0; qq < 4; ++qq) {
                cp  += pcf[r * 4 + qq];
                lsx += plc[r * 4 + qq];
                np  += pnp[r * 4 + qq];
            }
            s_scal[0] = cp; s_scal[1] = lsx; s_npos = np;
        }
    }
    __syncthreads();
    const int npos_row = s_npos;

    // ---- zero fixed-up priors in fv_b (every s_po entry ends positive)
#pragma unroll
    for (int i = 0; i < NP9; ++i) {
        int p = tid + i * NT;
#pragma unroll
        for (int j = 0; j < M_; ++j)
            if (s_po[j] == p) fv_b[i] = 0;
    }

    // ---- exact top-k over fp16 patterns: 15-step bisection, 1 barrier/iter
    int k = 3 * npos_row;
    if (k > P_) k = P_;
    float hard_sum = 0.0f;
    if (k > 0) {
        int lo = -1, hi = 0x7C00;   // invariant: cnt(lo)>=k, cnt(hi)<k
        for (int it = 0; it < 15; ++it) {
            int mid = (lo + hi) >> 1;
            int c = 0;
#pragma unroll
            for (int i = 0; i < NP9; ++i) c += (fv_b[i] > mid) ? 1 : 0;
            c = wred_sum_i(c);
            if (lane == 0) s_cnt2[it & 1][wid] = c;
            __syncthreads();
            int cnt = 0;
#pragma unroll
            for (int w = 0; w < NW; ++w) cnt += s_cnt2[it & 1][w];
            if (cnt < k) hi = mid; else lo = mid;
        }
        int tb = hi;                               // k-th largest fp16 pattern
        float tval = __half2float(__ushort_as_half((unsigned short)tb));
        float lsum = 0.0f; int lcnt = 0;
#pragma unroll
        for (int i = 0; i < NP9; ++i) {
            if (fv_b[i] > tb) {
                lsum += __half2float(__ushort_as_half((unsigned short)fv_b[i]));
                lcnt++;
            }
        }
        lsum = wred_sum_f(lsum);
        lcnt = wred_sum_i(lcnt);
        if (lane == 0) { s_pf[wid] = lsum; s_pi[wid] = lcnt; }
        __syncthreads();
        if (tid == 0) {
            float sv = 0.0f; int sc2 = 0;
#pragma unroll
            for (int w = 0; w < NW; ++w) { sv += s_pf[w]; sc2 += s_pi[w]; }
            hard_sum = sv + (float)(k - sc2) * tval;
        }
    }

    // ---- finalize
    if (tid == 0) {
        float conf_row = s_scal[0] + hard_sum;
        float loc_row  = s_scal[1];
        out[3 + r] = (float)npos_row;
        atomicAdd(g_conf, conf_row);
        atomicAdd(g_loc,  loc_row);
        atomicAdd(g_np,   npos_row);
        __threadfence();
        unsigned int done = atomicAdd(g_cnt, 1u);
        if (done == B_ - 1) {
            float ct = atomicAdd(g_conf, 0.0f);
            float lt = atomicAdd(g_loc,  0.0f);
            int   np = atomicAdd(g_np,   0);
            float npt = (float)np;
            float conf_loss = ct / (1e-10f + npt);
            float loc_loss = (np > 0) ? lt / (4.0f * fmaxf(npt, 1.0f)) : 0.0f;
            out[0] = conf_loss + loc_loss;   // ALPHA = 1
            out[1] = conf_loss;
            out[2] = loc_loss;
        }
    }
}

extern "C" void kernel_launch(void* const* d_in, const int* in_sizes, int n_in,
                              void* d_out, int out_size, void* d_ws, size_t ws_size,
                              hipStream_t stream) {
    const float* plocs   = (const float*)d_in[0];
    const float* pscores = (const float*)d_in[1];
    const float* boxes   = (const float*)d_in[2];
    const int*   labels  = (const int*)  d_in[3];
    const float* priors  = (const float*)d_in[4];
    float* out = (float*)d_out;

    // ws layout (~3.5 MB total):
    //   [0,16)        g_cnt, g_conf, g_loc, g_np
    //   [64, +2K)     pcf float[512]
    //   [2112, +2K)   plc float[512]
    //   [4160, +2K)   pnp int[512]
    //   [8192, +64K)  cand int2[512*16]
    //   [73728, +1117696)  objov bytes
    //   [1191424, +2235392) bcew fp16
    char* ws = (char*)d_ws;
    unsigned int* g_cnt  = (unsigned int*)ws;
    float*        g_conf = (float*)(ws + 4);
    float*        g_loc  = (float*)(ws + 8);
    int*          g_np   = (int*)(ws + 12);
    float*        pcf    = (float*)(ws + 64);
    float*        plc    = (float*)(ws + 2112);
    int*          pnp    = (int*)(ws + 4160);
    int2*         cand   = (int2*)(ws + 8192);
    unsigned char* objov = (unsigned char*)(ws + 73728);
    unsigned short* bcew = (unsigned short*)(ws + 73728 + (size_t)B_ * P_);

    mbox_match_kernel<<<4 * B_, NT, 0, stream>>>(plocs, pscores, boxes, labels, priors,
                                                 objov, bcew, cand, pcf, plc, pnp,
                                                 (unsigned int*)ws);
    mbox_loss_kernel<<<B_, NT, 0, stream>>>(plocs, pscores, boxes, labels, priors,
                                            objov, bcew, cand, pcf, plc, pnp,
                                            out, g_cnt, g_conf, g_loc, g_np);
}

// Round 13
// 120.118 us; speedup vs baseline: 1.6238x; 1.1351x over previous
//
#include <hip/hip_runtime.h>
#include <hip/hip_fp16.h>
#include <cstdint>
#include <cmath>

#define B_ 128
#define P_ 8732
#define QU_ 2183        // P_ / 4 exactly
#define M_ 16
#define NT 1024
#define NW 16           // waves per block == M_
#define NP9 9           // ceil(P_/NT)

// softplus via raw v_exp_f32/v_log_f32 (both ~1 ulp):
// softplus(x) = max(x,0) + ln2 * log2(1 + exp2(-|x|*log2e))
__device__ __forceinline__ float softplusf(float x) {
    float e = __builtin_amdgcn_exp2f(fabsf(x) * -1.44269504f);
    return fmaxf(x, 0.0f) + 0.69314718f * __builtin_amdgcn_logf(1.0f + e);
}

__device__ __forceinline__ float wred_sum_f(float v) {
#pragma unroll
    for (int o = 32; o > 0; o >>= 1) v += __shfl_down(v, o, 64);
    return v;
}
__device__ __forceinline__ int wred_sum_i(int v) {
#pragma unroll
    for (int o = 32; o > 0; o >>= 1) v += __shfl_down(v, o, 64);
    return v;
}

// ============ K1: fused match (A+B via LDS atomic-max) + BCE/L1. grid=512. ===
// Wave m owns object m. Per-p argmax over m via packed u64 LDS atomicMax
// ((bits(ov)<<4)|(15-m): lexicographic (ov, lowest-m) - exact first-max).
// Mailbox init = 15 (= m=0, ov=0), so ov==0 lanes SKIP the atomic: all-zero
// priors resolve to m=0 (JAX first-occurrence argmax), any ov>0 beats zeros.
__global__ __launch_bounds__(NT) void mbox_match_kernel(
    const float* __restrict__ plocs,   // (B,P,4)
    const float* __restrict__ pscores, // (B,P,3)
    const float* __restrict__ boxes,   // (B,M,4) xyxy
    const int*   __restrict__ labels,  // (B,M)
    const float* __restrict__ priors,  // (P,4) cxcy
    unsigned char* __restrict__ objov,
    unsigned short* __restrict__ bcew,
    int2* __restrict__ cand,
    float* __restrict__ pcf, float* __restrict__ plc, int* __restrict__ pnp,
    unsigned int* __restrict__ gz)     // 4 words to zero (g_cnt,g_conf,g_loc,g_np)
{
    __shared__ unsigned long long s_ovp[QU_];   // packed (ov_bits<<4)|(15-m)
    __shared__ float s_boxes[M_ * 4];
    __shared__ float s_area[M_];
    __shared__ int   s_labels[M_];
    __shared__ float s_pf[2 * NW];
    __shared__ int   s_pi[NW];

    const int bk = blockIdx.x;
    const int r  = bk >> 2;
    const int q  = bk & 3;
    const int tid = threadIdx.x;
    const int lane = tid & 63;
    const int wid = tid >> 6;

    if (bk == 0 && tid < 4) gz[tid] = 0u;   // zero global accumulators for K2

    if (tid < M_ * 4) s_boxes[tid] = boxes[r * M_ * 4 + tid];
    if (tid >= 64 && tid < 64 + M_) s_labels[tid - 64] = labels[r * M_ + (tid - 64)];
    for (int i = tid; i < QU_; i += NT) s_ovp[i] = 15ull;   // (ov=0, m=0)
    __syncthreads();
    if (tid < M_) {
        float x0 = s_boxes[tid*4+0], y0 = s_boxes[tid*4+1];
        float x1 = s_boxes[tid*4+2], y1 = s_boxes[tid*4+3];
        s_area[tid] = (x1 - x0) * (y1 - y0);
    }
    __syncthreads();

    const int p0 = q * QU_;

    // ---- Phase A+B fused: wave m scans the quarter once for object m
    {
        const int m = wid;
        const float bx0 = s_boxes[m*4+0], by0 = s_boxes[m*4+1];
        const float bx1 = s_boxes[m*4+2], by1 = s_boxes[m*4+3];
        const float marea = s_area[m];
        const unsigned long long tag = (unsigned long long)(15 - m);
        float bv = -1.0f; int bi = 0x7FFFFFFF;
        for (int p = p0 + lane; p < p0 + QU_; p += 64) {
            float4 pr = ((const float4*)priors)[p];
            float px0 = pr.x - pr.z * 0.5f;
            float py0 = pr.y - pr.w * 0.5f;
            float px1 = pr.x + pr.z * 0.5f;
            float py1 = pr.y + pr.w * 0.5f;
            float ltx = fmaxf(bx0, px0);
            float lty = fmaxf(by0, py0);
            float rbx = fminf(bx1, px1);
            float rby = fminf(by1, py1);
            float wx = fmaxf(rbx - ltx, 0.0f);
            float wy = fmaxf(rby - lty, 0.0f);
            float inter = wx * wy;
            float ov = inter * __builtin_amdgcn_rcpf(marea + pr.z * pr.w - inter);
            if (ov > 0.0f) {
                unsigned long long pk =
                    ((unsigned long long)__float_as_uint(ov) << 4) | tag;
                atomicMax(&s_ovp[p - p0], pk);
            }
            if (ov > bv) { bv = ov; bi = p; }   // first-max (p ascending per lane)
        }
#pragma unroll
        for (int o = 32; o > 0; o >>= 1) {
            float v2 = __shfl_down(bv, o, 64);
            int   i2 = __shfl_down(bi, o, 64);
            if (v2 > bv || (v2 == bv && i2 < bi)) { bv = v2; bi = i2; }
        }
        if (lane == 0) cand[bk * M_ + m] = make_int2(__float_as_int(bv), bi);
    }
    __syncthreads();

    // ---- Phase D: unpack per-prior best, bce/l1, partials
    int np = 0; float cp = 0.0f, ls = 0.0f;
    for (int p = p0 + tid; p < p0 + QU_; p += NT) {
        unsigned long long u = s_ovp[p - p0];
        int   besti = 15 - (int)(u & 15ull);
        float bestv = __uint_as_float((unsigned int)(u >> 4));
        bool pos = bestv >= 0.5f;
        objov[(size_t)r * P_ + p] = (unsigned char)(besti | (pos ? 0x80 : 0));

        const float* sc = pscores + ((size_t)r * P_ + p) * 3;
        float x0 = sc[0], x1 = sc[1], x2 = sc[2];
        int lab = pos ? s_labels[besti] : 0;
        float t0 = (lab == 0) ? 1.0f : 0.0f;
        float t1 = (lab == 1 || lab == 3) ? 1.0f : 0.0f;
        float t2 = (lab == 2 || lab == 3) ? 1.0f : 0.0f;
        float bce = (softplusf(x0) - x0*t0) + (softplusf(x1) - x1*t1) + (softplusf(x2) - x2*t2);
        float hb = 0.0f;
        if (pos) {
            np++; cp += bce;
            float4 pr = ((const float4*)priors)[p];
            float bx0 = s_boxes[besti*4+0], by0 = s_boxes[besti*4+1];
            float bx1 = s_boxes[besti*4+2], by1 = s_boxes[besti*4+3];
            float cx = (bx0 + bx1) * 0.5f, cy = (by0 + by1) * 0.5f;
            float w = bx1 - bx0, hh = by1 - by0;
            float g0 = (cx - pr.x) / (pr.z * 0.1f);
            float g1 = (cy - pr.y) / (pr.w * 0.1f);
            float g2 = logf(w / pr.z) * 5.0f;
            float g3 = logf(hh / pr.w) * 5.0f;
            float4 pl = ((const float4*)plocs)[(size_t)r * P_ + p];
            ls += fabsf(pl.x - g0) + fabsf(pl.y - g1) + fabsf(pl.z - g2) + fabsf(pl.w - g3);
        } else {
            hb = bce;
        }
        bcew[(size_t)r * P_ + p] = __half_as_ushort(__float2half(hb));
    }

    // ---- reduce quarter partials
    {
        float cpr = wred_sum_f(cp);
        float lsr = wred_sum_f(ls);
        int   npr = wred_sum_i(np);
        if (lane == 0) { s_pf[wid] = cpr; s_pf[NW + wid] = lsr; s_pi[wid] = npr; }
    }
    __syncthreads();
    if (tid == 0) {
        float c2 = 0.0f, l2 = 0.0f; int n2 = 0;
#pragma unroll
        for (int w = 0; w < NW; ++w) { c2 += s_pf[w]; l2 += s_pf[NW + w]; n2 += s_pi[w]; }
        pcf[bk] = c2; plc[bk] = l2; pnp[bk] = n2;
    }
}

// ============ K2: parallel fixup correction + hard-neg mining. grid = 128. ===
__global__ __launch_bounds__(NT) void mbox_loss_kernel(
    const float* __restrict__ plocs,
    const float* __restrict__ pscores,
    const float* __restrict__ boxes,
    const int*   __restrict__ labels,
    const float* __restrict__ priors,
    const unsigned char* __restrict__ objov,
    const unsigned short* __restrict__ bcew,
    const int2* __restrict__ cand,
    const float* __restrict__ pcf, const float* __restrict__ plc,
    const int* __restrict__ pnp,
    float* __restrict__ out,
    unsigned int* __restrict__ g_cnt,
    float* __restrict__ g_conf, float* __restrict__ g_loc, int* __restrict__ g_np)
{
    __shared__ float s_boxes[M_ * 4];
    __shared__ int   s_labels[M_];
    __shared__ int   s_po[M_];
    __shared__ float s_pf[2 * NW];
    __shared__ int   s_pi[NW];
    __shared__ int   s_cnt2[2][NW];
    __shared__ float s_scal[2];
    __shared__ int   s_npos;

    const int r = blockIdx.x;
    const int tid = threadIdx.x;
    const int lane = tid & 63;
    const int wid = tid >> 6;

    if (tid < M_ * 4) s_boxes[tid] = boxes[r * M_ * 4 + tid];
    if (tid >= 64 && tid < 64 + M_) s_labels[tid - 64] = labels[r * M_ + (tid - 64)];
    if (tid >= 128 && tid < 128 + M_) {
        int m = tid - 128;
        int2 c = cand[(r * 4) * M_ + m];
        float v = __int_as_float(c.x); int idx = c.y;
#pragma unroll
        for (int qq = 1; qq < 4; ++qq) {
            int2 c2 = cand[(r * 4 + qq) * M_ + m];
            float v2 = __int_as_float(c2.x);
            if (v2 > v) { v = v2; idx = c2.y; }   // strict >: earliest quarter wins ties
        }
        s_po[m] = idx;
    }
    __syncthreads();

    // ---- load neg bce early (independent of fixup -> latency overlap)
    int fv_b[NP9];
#pragma unroll
    for (int i = 0; i < NP9; ++i) {
        int p = tid + i * NT;
        fv_b[i] = (p < P_) ? (int)bcew[(size_t)r * P_ + p] : 0;
    }

    // ---- PARALLEL fixup: lane m of wave 0 owns object m; "last m wins" =>
    //      owner iff no m' > m maps to the same prior. Register-only.
    if (wid == 0) {
        float dcp = 0.0f, dls = 0.0f; int dnp = 0;
        if (lane < M_) {
            const int m = lane;
            const int idx = s_po[m];
            bool owner = true;
            for (int m2 = m + 1; m2 < M_; ++m2)
                if (s_po[m2] == idx) owner = false;
            if (owner) {
                unsigned char byte = objov[(size_t)r * P_ + idx];
                bool oldpos = (byte & 0x80) != 0;
                int  oldobj = byte & 15;
                const float* sc = pscores + ((size_t)r * P_ + idx) * 3;
                float x0 = sc[0], x1 = sc[1], x2 = sc[2];
                float S = softplusf(x0) + softplusf(x1) + softplusf(x2);
                float4 pr = ((const float4*)priors)[idx];
                float4 pl = ((const float4*)plocs)[(size_t)r * P_ + idx];
                {
                    int lab = s_labels[m];
                    float t0 = (lab == 0) ? 1.0f : 0.0f;
                    float t1 = (lab == 1 || lab == 3) ? 1.0f : 0.0f;
                    float t2 = (lab == 2 || lab == 3) ? 1.0f : 0.0f;
                    dcp += S - (x0*t0 + x1*t1 + x2*t2);
                    float bx0 = s_boxes[m*4+0], by0 = s_boxes[m*4+1];
                    float bx1 = s_boxes[m*4+2], by1 = s_boxes[m*4+3];
                    float cx = (bx0+bx1)*0.5f, cy = (by0+by1)*0.5f;
                    float w = bx1-bx0, hh = by1-by0;
                    float g0 = (cx - pr.x) / (pr.z * 0.1f);
                    float g1 = (cy - pr.y) / (pr.w * 0.1f);
                    float g2 = logf(w / pr.z) * 5.0f;
                    float g3 = logf(hh / pr.w) * 5.0f;
                    dls += fabsf(pl.x-g0)+fabsf(pl.y-g1)+fabsf(pl.z-g2)+fabsf(pl.w-g3);
                    dnp += 1;
                }
                if (oldpos) {
                    int lab = s_labels[oldobj];
                    float t0 = (lab == 0) ? 1.0f : 0.0f;
                    float t1 = (lab == 1 || lab == 3) ? 1.0f : 0.0f;
                    float t2 = (lab == 2 || lab == 3) ? 1.0f : 0.0f;
                    dcp -= S - (x0*t0 + x1*t1 + x2*t2);
                    float bx0 = s_boxes[oldobj*4+0], by0 = s_boxes[oldobj*4+1];
                    float bx1 = s_boxes[oldobj*4+2], by1 = s_boxes[oldobj*4+3];
                    float cx = (bx0+bx1)*0.5f, cy = (by0+by1)*0.5f;
                    float w = bx1-bx0, hh = by1-by0;
                    float g0 = (cx - pr.x) / (pr.z * 0.1f);
                    float g1 = (cy - pr.y) / (pr.w * 0.1f);
                    float g2 = logf(w / pr.z) * 5.0f;
                    float g3 = logf(hh / pr.w) * 5.0f;
                    dls -= fabsf(pl.x-g0)+fabsf(pl.y-g1)+fabsf(pl.z-g2)+fabsf(pl.w-g3);
                    dnp -= 1;
                }
            }
        }
        dcp = wred_sum_f(dcp);
        dls = wred_sum_f(dls);
        dnp = wred_sum_i(dnp);
        if (lane == 0) {
            float cp = dcp, lsx = dls; int np = dnp;
#pragma unroll
            for (int qq = 0; qq < 4; ++qq) {
                cp  += pcf[r * 4 + qq];
                lsx += plc[r * 4 + qq];
                np  += pnp[r * 4 + qq];
            }
            s_scal[0] = cp; s_scal[1] = lsx; s_npos = np;
        }
    }
    __syncthreads();
    const int npos_row = s_npos;

    // ---- zero fixed-up priors in fv_b (every s_po entry ends positive)
#pragma unroll
    for (int i = 0; i < NP9; ++i) {
        int p = tid + i * NT;
#pragma unroll
        for (int j = 0; j < M_; ++j)
            if (s_po[j] == p) fv_b[i] = 0;
    }

    // ---- exact top-k over fp16 patterns: 15-step bisection, 1 barrier/iter
    int k = 3 * npos_row;
    if (k > P_) k = P_;
    float hard_sum = 0.0f;
    if (k > 0) {
        int lo = -1, hi = 0x7C00;   // invariant: cnt(lo)>=k, cnt(hi)<k
        for (int it = 0; it < 15; ++it) {
            int mid = (lo + hi) >> 1;
            int c = 0;
#pragma unroll
            for (int i = 0; i < NP9; ++i) c += (fv_b[i] > mid) ? 1 : 0;
            c = wred_sum_i(c);
            if (lane == 0) s_cnt2[it & 1][wid] = c;
            __syncthreads();
            int cnt = 0;
#pragma unroll
            for (int w = 0; w < NW; ++w) cnt += s_cnt2[it & 1][w];
            if (cnt < k) hi = mid; else lo = mid;
        }
        int tb = hi;                               // k-th largest fp16 pattern
        float tval = __half2float(__ushort_as_half((unsigned short)tb));
        float lsum = 0.0f; int lcnt = 0;
#pragma unroll
        for (int i = 0; i < NP9; ++i) {
            if (fv_b[i] > tb) {
                lsum += __half2float(__ushort_as_half((unsigned short)fv_b[i]));
                lcnt++;
            }
        }
        lsum = wred_sum_f(lsum);
        lcnt = wred_sum_i(lcnt);
        if (lane == 0) { s_pf[wid] = lsum; s_pi[wid] = lcnt; }
        __syncthreads();
        if (tid == 0) {
            float sv = 0.0f; int sc2 = 0;
#pragma unroll
            for (int w = 0; w < NW; ++w) { sv += s_pf[w]; sc2 += s_pi[w]; }
            hard_sum = sv + (float)(k - sc2) * tval;
        }
    }

    // ---- finalize
    if (tid == 0) {
        float conf_row = s_scal[0] + hard_sum;
        float loc_row  = s_scal[1];
        out[3 + r] = (float)npos_row;
        atomicAdd(g_conf, conf_row);
        atomicAdd(g_loc,  loc_row);
        atomicAdd(g_np,   npos_row);
        __threadfence();
        unsigned int done = atomicAdd(g_cnt, 1u);
        if (done == B_ - 1) {
            float ct = atomicAdd(g_conf, 0.0f);
            float lt = atomicAdd(g_loc,  0.0f);
            int   np = atomicAdd(g_np,   0);
            float npt = (float)np;
            float conf_loss = ct / (1e-10f + npt);
            float loc_loss = (np > 0) ? lt / (4.0f * fmaxf(npt, 1.0f)) : 0.0f;
            out[0] = conf_loss + loc_loss;   // ALPHA = 1
            out[1] = conf_loss;
            out[2] = loc_loss;
        }
    }
}

extern "C" void kernel_launch(void* const* d_in, const int* in_sizes, int n_in,
                              void* d_out, int out_size, void* d_ws, size_t ws_size,
                              hipStream_t stream) {
    const float* plocs   = (const float*)d_in[0];
    const float* pscores = (const float*)d_in[1];
    const float* boxes   = (const float*)d_in[2];
    const int*   labels  = (const int*)  d_in[3];
    const float* priors  = (const float*)d_in[4];
    float* out = (float*)d_out;

    // ws layout (~3.5 MB total):
    //   [0,16)        g_cnt, g_conf, g_loc, g_np
    //   [64, +2K)     pcf float[512]
    //   [2112, +2K)   plc float[512]
    //   [4160, +2K)   pnp int[512]
    //   [8192, +64K)  cand int2[512*16]
    //   [73728, +1117696)  objov bytes
    //   [1191424, +2235392) bcew fp16
    char* ws = (char*)d_ws;
    unsigned int* g_cnt  = (unsigned int*)ws;
    float*        g_conf = (float*)(ws + 4);
    float*        g_loc  = (float*)(ws + 8);
    int*          g_np   = (int*)(ws + 12);
    float*        pcf    = (float*)(ws + 64);
    float*        plc    = (float*)(ws + 2112);
    int*          pnp    = (int*)(ws + 4160);
    int2*         cand   = (int2*)(ws + 8192);
    unsigned char* objov = (unsigned char*)(ws + 73728);
    unsigned short* bcew = (unsigned short*)(ws + 73728 + (size_t)B_ * P_);

    mbox_match_kernel<<<4 * B_, NT, 0, stream>>>(plocs, pscores, boxes, labels, priors,
                                                 objov, bcew, cand, pcf, plc, pnp,
                                                 (unsigned int*)ws);
    mbox_loss_kernel<<<B_, NT, 0, stream>>>(plocs, pscores, boxes, labels, priors,
                                            objov, bcew, cand, pcf, plc, pnp,
                                            out, g_cnt, g_conf, g_loc, g_np);
}